// Round 13
// baseline (231.568 us; speedup 1.0000x reference)
//
#include <hip/hip_runtime.h>

// Levenshtein edit distance, ref (512,B) x hyp (512,B), B=1024, unit costs.
// One 64-lane wave per problem, 8 cells/lane parity-packed (reg p = cells
// {8l+p, 8l+p+4}), anti-diagonal wavefront, hand-scheduled single asm block
// per step (r12 structure, absmax=0-verified algebra).
//
// Round-13 change (discriminating experiment): cross-lane traffic merged
// into ONE DPP. M = {lo: q3.hi, hi: a13.hi} via v_perm; one v_mov_b32_dpp
// wave_shr:1 moves both seams; alignbit + v_perm unpack. Lane-0 boundary:
// Md's lane 0 is PRESERVED by DPP (bound_ctrl off, r12-verified) and
// pre-loaded by v_writelane with an SALU-packed scalar {hyp[d-1] | 0x400<<16}
// -> tokens come from uniform scalar loads (SMEM co-issue, zero VALU),
// deleting LDS staging + token movs. 29 VALU/step, 1 DPP.
//
// Biased relative domain (r7-r12-verified): w = v - d + 1024 in [0,1024].
//   AN[p] = min(a1s[p], A1[p], A2[p-1] + nq - 2), nq = min_u16(ref^hyp, 1),
//   nq-2 via OR 0xFFFE. i=0 boundary: 1024 hi-half via Md lane 0.
//   j=0 boundary: FAKE init. Answer: w = v at d = 1024.

#define BATCH 1024
#define HLEN 512
#define FAKE2  0x3FFF3FFFu  // packed fake-infinity
#define SENT2  0x03FF03FFu  // packed sentinel tokens (real tokens < 1000)
#define ONE2   0x00010001u
#define NEG22  0xFFFEFFFEu
#define SEL_M  0x07060302u  // M  = {b0:q3.b2, b1:q3.b3, b2:a13.b2, b3:a13.b3}
#define SEL_Q  0x05040100u  // qn = {b0:Md.b0, b1:Md.b1, b2:q3.b0, b3:q3.b1}

// X = A2-in / AN-out (in-place). Y = A1 (read-only). Q0..Q2 older queue
// regs (read-only), Q3 = oldest, replaced by shifted queue. SA = carried
// shifted-A2 seam (read), SB = new shifted-A1 seam (written). ST = scalar
// pack for NEXT step's lane-0 injection: {lo: token, hi: 0x0400}.
#define STEP(X, Y, Q0, Q1, Q2, Q3, SA, SB, ST)                          \
  {                                                                     \
    unsigned m, x0, x1, x2, x3, e1, e2, e3, dv;                         \
    asm("v_perm_b32 %[m], %[y3], %[q3], %[selm]\n\t"                    \
        "v_xor_b32 %[x1], %[rt1], %[vq0]\n\t"                           \
        "v_xor_b32 %[x2], %[rt2], %[vq1]\n\t"                           \
        "v_xor_b32 %[x3], %[rt3], %[vq2]\n\t"                           \
        "v_mov_b32_dpp %[md], %[m] wave_shr:1 row_mask:0xf bank_mask:0xf\n\t" \
        "v_pk_min_u16 %[x1], %[x1], %[one]\n\t"                         \
        "v_pk_min_u16 %[x2], %[x2], %[one]\n\t"                         \
        "v_pk_min_u16 %[x3], %[x3], %[one]\n\t"                         \
        "v_pk_min_u16 %[e1], %[y0], %[y1]\n\t"                          \
        "v_alignbit_b32 %[sb], %[y3], %[md], 16\n\t"                    \
        "v_perm_b32 %[q3], %[q3], %[md], %[selq]\n\t"                   \
        "v_or_b32 %[x1], %[x1], %[neg2]\n\t"                            \
        "v_or_b32 %[x2], %[x2], %[neg2]\n\t"                            \
        "v_or_b32 %[x3], %[x3], %[neg2]\n\t"                            \
        "v_xor_b32 %[x0], %[rt0], %[q3]\n\t"                            \
        "v_pk_add_u16 %[x1], %[xb0], %[x1]\n\t"                         \
        "v_pk_add_u16 %[x2], %[xb1], %[x2]\n\t"                         \
        "v_pk_add_u16 %[x3], %[xb2], %[x3]\n\t"                         \
        "v_pk_min_u16 %[x0], %[x0], %[one]\n\t"                         \
        "v_pk_min_u16 %[e2], %[y1], %[y2]\n\t"                          \
        "v_pk_min_u16 %[e3], %[y2], %[y3]\n\t"                          \
        "v_or_b32 %[x0], %[x0], %[neg2]\n\t"                            \
        "v_pk_add_u16 %[x0], %[sa], %[x0]\n\t"                          \
        "v_pk_min_u16 %[dv], %[sb], %[y0]\n\t"                          \
        "v_pk_min_u16 %[xb1], %[e1], %[x1]\n\t"                         \
        "v_pk_min_u16 %[xb2], %[e2], %[x2]\n\t"                         \
        "v_pk_min_u16 %[xb3], %[e3], %[x3]\n\t"                         \
        "v_pk_min_u16 %[xb0], %[dv], %[x0]\n\t"                         \
        "v_writelane_b32 %[md], %[st], 0"                               \
        : [xb0] "+v"(X[0]), [xb1] "+v"(X[1]), [xb2] "+v"(X[2]),         \
          [xb3] "+v"(X[3]), [q3] "+v"(Q3), [sb] "=&v"(SB),              \
          [md] "+v"(md),                                                \
          [m] "=&v"(m), [x0] "=&v"(x0), [x1] "=&v"(x1),                 \
          [x2] "=&v"(x2), [x3] "=&v"(x3), [e1] "=&v"(e1),               \
          [e2] "=&v"(e2), [e3] "=&v"(e3), [dv] "=&v"(dv)                \
        : [y0] "v"(Y[0]), [y1] "v"(Y[1]), [y2] "v"(Y[2]),               \
          [y3] "v"(Y[3]), [vq0] "v"(Q0), [vq1] "v"(Q1),                 \
          [vq2] "v"(Q2), [sa] "v"(SA),                                  \
          [rt0] "v"(rt[0]), [rt1] "v"(rt[1]),                           \
          [rt2] "v"(rt[2]), [rt3] "v"(rt[3]), [one] "v"(one2),          \
          [neg2] "v"(neg2), [selm] "v"(selm), [selq] "v"(selq),         \
          [st] "s"(ST));                                                \
  }

__global__ void __launch_bounds__(64)
edit_distance_kernel(const int* __restrict__ ref,
                     const int* __restrict__ hyp,
                     float* __restrict__ out) {
  const int b = blockIdx.x;        // one wave (block of 64) per batch element
  const int lane = threadIdx.x;    // 0..63

  // Parity-packed static ref tokens: rt[p] = {cell 8l+p, cell 8l+p+4}.
  unsigned rt[4];
#pragma unroll
  for (int p = 0; p < 4; ++p) {
    unsigned lo = (unsigned)ref[(lane * 8 + p) * BATCH + b];
    unsigned hi = (unsigned)ref[(lane * 8 + p + 4) * BATCH + b];
    rt[p] = lo | (hi << 16);
  }

  const unsigned one2 = ONE2, neg2 = NEG22, selm = SEL_M, selq = SEL_Q;

  // X = diag 0 (all fake), Y = diag 1 (lane0 cell0: w = 1024).
  unsigned X[4], Y[4];
  X[0] = X[1] = X[2] = X[3] = FAKE2;
  Y[0] = Y[1] = Y[2] = Y[3] = FAKE2;
  unsigned q0 = SENT2, q1 = SENT2, q2 = SENT2, q3 = SENT2;
  unsigned sA = FAKE2, sB = FAKE2;  // shifted-seam ping-pong (period 2)
  if (lane == 0) { Y[0] = 0x3FFF0400u; sA = 0x3FFF0400u; }

  // Md: lane 0 = {lo: inject token for d=2 (hyp[0]), hi: 0x0400 boundary}.
  // Other lanes are junk; the first DPP overwrites lanes 1..63 before use.
  unsigned md = ((unsigned)hyp[b] & 0xFFFFu) | 0x04000000u;

  // Scalar token packs (uniform loads -> SMEM/SALU): step d = 2+k writes
  // next-step pack hyp[d-1] => tp[j] = hyp[1 + 12*it + j] | 0x0400<<16.
  unsigned tp[12], tn[12];
#pragma unroll
  for (int j = 0; j < 12; ++j)
    tp[j] = ((unsigned)hyp[(j + 1) * BATCH + b] & 0xFFFFu) | 0x04000000u;

  // 85 iterations x 12 steps = diags 2..1021.
  for (int it = 0; it < 85; ++it) {
    const int base = 13 + it * 12;
#pragma unroll
    for (int j = 0; j < 12; ++j)
      tn[j] = ((unsigned)hyp[min(base + j, HLEN - 1) * BATCH + b] & 0xFFFFu)
              | 0x04000000u;
    STEP(X, Y, q0, q1, q2, q3, sA, sB, tp[0]);
    STEP(Y, X, q3, q0, q1, q2, sB, sA, tp[1]);
    STEP(X, Y, q2, q3, q0, q1, sA, sB, tp[2]);
    STEP(Y, X, q1, q2, q3, q0, sB, sA, tp[3]);
    STEP(X, Y, q0, q1, q2, q3, sA, sB, tp[4]);
    STEP(Y, X, q3, q0, q1, q2, sB, sA, tp[5]);
    STEP(X, Y, q2, q3, q0, q1, sA, sB, tp[6]);
    STEP(Y, X, q1, q2, q3, q0, sB, sA, tp[7]);
    STEP(X, Y, q0, q1, q2, q3, sA, sB, tp[8]);
    STEP(Y, X, q3, q0, q1, q2, sB, sA, tp[9]);
    STEP(X, Y, q2, q3, q0, q1, sA, sB, tp[10]);
    STEP(Y, X, q1, q2, q3, q0, sB, sA, tp[11]);
#pragma unroll
    for (int j = 0; j < 12; ++j) tp[j] = tn[j];
  }

  // Epilogue: diags 1022, 1023, 1024 (tokens clamped -> junk j>511 cells).
  STEP(X, Y, q0, q1, q2, q3, sA, sB, tp[0]);  // X <- 1022
  STEP(Y, X, q3, q0, q1, q2, sB, sA, tp[1]);  // Y <- 1023
  STEP(X, Y, q2, q3, q0, q1, sA, sB, tp[2]);  // X <- 1024

  // Answer: cell 511 = lane 63, pair 3, HIGH half; at d = 1024, w = v.
  if (lane == 63) out[b] = (float)(X[3] >> 16);
}

extern "C" void kernel_launch(void* const* d_in, const int* in_sizes, int n_in,
                              void* d_out, int out_size, void* d_ws, size_t ws_size,
                              hipStream_t stream) {
  const int* ref = (const int*)d_in[0];
  const int* hyp = (const int*)d_in[1];
  float* out = (float*)d_out;
  edit_distance_kernel<<<BATCH, 64, 0, stream>>>(ref, hyp, out);
}